// Round 3
// baseline (152.751 us; speedup 1.0000x reference)
//
#include <hip/hip_runtime.h>

#define BB 32
#define SS 512
#define DD 768
#define NROW (BB * SS)  // 16384 rows per input

typedef float f32x4 __attribute__((ext_vector_type(4)));
typedef short bf16x8 __attribute__((ext_vector_type(8)));

// order-preserving float -> uint key (monotone under unsigned compare)
__device__ __forceinline__ unsigned fkey(float f) {
  unsigned u = __float_as_uint(f);
  return (u & 0x80000000u) ? ~u : (u | 0x80000000u);
}
__device__ __forceinline__ float fdecode(unsigned k) {
  return __uint_as_float((k & 0x80000000u) ? (k & 0x7fffffffu) : ~k);
}
// f32 -> bf16 round-to-nearest-even
__device__ __forceinline__ unsigned short cvt_bf16(float f) {
  unsigned u = __float_as_uint(f);
  u += 0x7fffu + ((u >> 16) & 1u);
  return (unsigned short)(u >> 16);
}

// ---------------- K0: valid-index compaction + key init ----------------
// one wave per (batch, side). Ballot prefix-sum; pad idx to multiple of 128
// with duplicates of the last valid row (harmless: same atomicMax target/value).
__global__ __launch_bounds__(64) void index_kernel(
    const int* __restrict__ mask1, const int* __restrict__ mask2,
    int* __restrict__ idx1, int* __restrict__ idx2,
    int* __restrict__ nt1, int* __restrict__ nt2,
    unsigned* __restrict__ rowkey, unsigned* __restrict__ colkey) {
  int side = blockIdx.x & 1, b = blockIdx.x >> 1;
  const int* m = (side ? mask2 : mask1) + b * SS;
  unsigned* key = (side ? colkey : rowkey) + b * SS;
  int* idx = (side ? idx2 : idx1) + b * SS;
  int l = threadIdx.x;
  int nv = 0, lastelem = 0;
#pragma unroll
  for (int c = 0; c < 8; ++c) {
    int e = c * 64 + l;
    int v = m[e];
    key[e] = 0x007fffffu;  // fkey(-inf)
    unsigned long long bal = __ballot(v != 0);
    int pos = nv + __popcll(bal & ((1ull << l) - 1ull));
    if (v) idx[pos] = e;
    nv += __popcll(bal);
    if (bal) lastelem = c * 64 + (63 - __clzll(bal));
  }
  int nt = (nv + 127) >> 7;  // tiles of 128
  for (int p = nv + l; p < nt * 128; p += 64) idx[p] = lastelem;
  if (l == 0) (side ? nt2 : nt1)[b] = nt;
}

// ---------------- K1: normalize valid rows -> bf16, LINEAR layout ----------------
__global__ __launch_bounds__(256) void norm_cvt_kernel(
    const float* __restrict__ emb1, const float* __restrict__ emb2,
    const int* __restrict__ mask1, const int* __restrict__ mask2,
    unsigned short* __restrict__ wsA, unsigned short* __restrict__ wsB) {
  int wave = blockIdx.x * 4 + (threadIdx.x >> 6);  // 32768 waves
  int lane = threadIdx.x & 63;
  int half = wave >> 14;
  int r = wave & (NROW - 1);
  if ((half ? mask2 : mask1)[r] == 0) return;  // wave-uniform skip
  const float* src = (half ? emb2 : emb1) + (size_t)r * DD;
  float4 v[3];
  float s = 0.f;
#pragma unroll
  for (int q = 0; q < 3; ++q) {
    v[q] = ((const float4*)src)[q * 64 + lane];
    s += v[q].x * v[q].x + v[q].y * v[q].y + v[q].z * v[q].z + v[q].w * v[q].w;
  }
#pragma unroll
  for (int m = 1; m < 64; m <<= 1) s += __shfl_xor(s, m);
  float inv = 1.0f / fmaxf(sqrtf(s), 1e-8f);
  unsigned short* dst = (half ? wsB : wsA) + (size_t)r * DD;
#pragma unroll
  for (int q = 0; q < 3; ++q) {
    ushort4 u;
    u.x = cvt_bf16(v[q].x * inv); u.y = cvt_bf16(v[q].y * inv);
    u.z = cvt_bf16(v[q].z * inv); u.w = cvt_bf16(v[q].w * inv);
    *(ushort4*)(dst + q * 256 + lane * 4) = u;  // coalesced linear
  }
}

// ---------------- K2: bf16 MFMA on compacted valid rows + row/col max ----------------
// 128x128 tile, BK=64, 4 waves (2x2 of 64x64). Gather via idx lists in the
// per-lane gload_lds SOURCE address (XOR chunk swizzle there too; LDS linear).
__global__ __launch_bounds__(256) void simmax_kernel(
    const unsigned short* __restrict__ wsA, const unsigned short* __restrict__ wsB,
    const int* __restrict__ idx1, const int* __restrict__ idx2,
    const int* __restrict__ nt1, const int* __restrict__ nt2,
    unsigned* __restrict__ rowkey, unsigned* __restrict__ colkey) {
  int x = blockIdx.x;
  int b = x & 31;          // stride-32 tiles => all tiles of a batch on XCD b&7
  int tile = x >> 5;
  int ti = tile >> 2, tj = tile & 3;
  if (ti >= nt1[b] || tj >= nt2[b]) return;
  int i0 = ti << 7, j0 = tj << 7;
  __shared__ __align__(16) unsigned short sA[2][128 * 64];
  __shared__ __align__(16) unsigned short sB[2][128 * 64];
  int t = threadIdx.x, l = t & 63, wid = t >> 6, wr = wid >> 1, wc = wid & 1;
  int rsub = l >> 3, csub = l & 7;  // lane -> (row-in-8, 16B-chunk slot)
  // gather row indices for this lane's staging slots
  int ra[4], rb[4];
#pragma unroll
  for (int j = 0; j < 4; ++j) {
    int rowblk = (wid * 4 + j) * 8;
    ra[j] = idx1[b * SS + i0 + rowblk + rsub];
    rb[j] = idx2[b * SS + j0 + rowblk + rsub];
  }
  const unsigned short* gA = wsA + (size_t)b * SS * DD;
  const unsigned short* gB = wsB + (size_t)b * SS * DD;
  int csw = (csub ^ rsub) << 3;  // XOR-swizzled source chunk (elements)

  f32x4 acc[4][4] = {};

#define STAGE(buf, k0)                                                              \
  {                                                                                 \
    _Pragma("unroll") for (int j = 0; j < 4; ++j) {                                 \
      int rowblk = (wid * 4 + j) * 8;                                               \
      const unsigned short* ga = gA + (size_t)ra[j] * DD + (k0) + csw;              \
      const unsigned short* gb = gB + (size_t)rb[j] * DD + (k0) + csw;              \
      __builtin_amdgcn_global_load_lds(                                             \
          (const __attribute__((address_space(1))) unsigned int*)ga,                \
          (__attribute__((address_space(3))) unsigned int*)&sA[buf][rowblk * 64],   \
          16, 0, 0);                                                                \
      __builtin_amdgcn_global_load_lds(                                             \
          (const __attribute__((address_space(1))) unsigned int*)gb,                \
          (__attribute__((address_space(3))) unsigned int*)&sB[buf][rowblk * 64],   \
          16, 0, 0);                                                                \
    }                                                                               \
  }

  STAGE(0, 0);
  __syncthreads();
  int cur = 0;
#pragma unroll 1
  for (int tk = 0; tk < 12; ++tk) {
    if (tk < 11) STAGE(cur ^ 1, (tk + 1) * 64);
#pragma unroll
    for (int kk = 0; kk < 2; ++kk) {
      bf16x8 af[4], bfr[4];
#pragma unroll
      for (int mi = 0; mi < 4; ++mi) {
        int r = wr * 64 + mi * 16 + (l & 15);
        int ch = (kk << 2) + (l >> 4);
        af[mi] = *(const bf16x8*)(&sA[cur][(r << 6) + ((ch ^ (r & 7)) << 3)]);
      }
#pragma unroll
      for (int ni = 0; ni < 4; ++ni) {
        int r = wc * 64 + ni * 16 + (l & 15);
        int ch = (kk << 2) + (l >> 4);
        bfr[ni] = *(const bf16x8*)(&sB[cur][(r << 6) + ((ch ^ (r & 7)) << 3)]);
      }
#pragma unroll
      for (int mi = 0; mi < 4; ++mi)
#pragma unroll
        for (int ni = 0; ni < 4; ++ni)
          acc[mi][ni] = __builtin_amdgcn_mfma_f32_16x16x32_bf16(af[mi], bfr[ni], acc[mi][ni], 0, 0, 0);
    }
    __syncthreads();
    cur ^= 1;
  }

  // ---- epilogue: row/col max (all rows valid), scatter through idx ----
  const float NEG = -__builtin_inff();
  float rmax[4][4], cmax[4];
#pragma unroll
  for (int mi = 0; mi < 4; ++mi)
#pragma unroll
    for (int rg = 0; rg < 4; ++rg) rmax[mi][rg] = NEG;
#pragma unroll
  for (int ni = 0; ni < 4; ++ni) cmax[ni] = NEG;

#pragma unroll
  for (int mi = 0; mi < 4; ++mi)
#pragma unroll
    for (int ni = 0; ni < 4; ++ni)
#pragma unroll
      for (int rg = 0; rg < 4; ++rg) {
        float v = acc[mi][ni][rg];
        rmax[mi][rg] = fmaxf(rmax[mi][rg], v);
        cmax[ni] = fmaxf(cmax[ni], v);
      }
#pragma unroll
  for (int mi = 0; mi < 4; ++mi)
#pragma unroll
    for (int rg = 0; rg < 4; ++rg) {
      float v = rmax[mi][rg];
      v = fmaxf(v, __shfl_xor(v, 1));
      v = fmaxf(v, __shfl_xor(v, 2));
      v = fmaxf(v, __shfl_xor(v, 4));
      v = fmaxf(v, __shfl_xor(v, 8));
      rmax[mi][rg] = v;
    }
#pragma unroll
  for (int ni = 0; ni < 4; ++ni) {
    float v = cmax[ni];
    v = fmaxf(v, __shfl_xor(v, 16));
    v = fmaxf(v, __shfl_xor(v, 32));
    cmax[ni] = v;
  }
  int selm = (l >> 2) & 3, selr = l & 3, seln = (l >> 4) & 3;
  float rv = rmax[0][0], cv = cmax[0];
#pragma unroll
  for (int mi = 0; mi < 4; ++mi)
#pragma unroll
    for (int rg = 0; rg < 4; ++rg)
      if (selm == mi && selr == rg) rv = rmax[mi][rg];
#pragma unroll
  for (int ni = 0; ni < 4; ++ni)
    if (seln == ni) cv = cmax[ni];
  int rl = selm * 16 + ((l >> 4) & 3) * 4 + selr;  // bijection over 64 rows
  int cl = seln * 16 + (l & 15);                   // bijection over 64 cols
  int orow = idx1[b * SS + i0 + wr * 64 + rl];
  int ocol = idx2[b * SS + j0 + wc * 64 + cl];
  atomicMax(&rowkey[b * SS + orow], fkey(rv));
  atomicMax(&colkey[b * SS + ocol], fkey(cv));
}

// ---------------- K3: finalize scores ----------------
__global__ __launch_bounds__(256) void finalize_kernel(
    const int* __restrict__ mask1, const int* __restrict__ mask2,
    const unsigned* __restrict__ rowkey, const unsigned* __restrict__ colkey,
    float* __restrict__ out) {
  int b = blockIdx.x, t = threadIdx.x;
  float sum = 0.f;
  int cnt = 0;
  for (int s = t; s < SS; s += 256) {
    if (mask1[b * SS + s]) { sum += fdecode(rowkey[b * SS + s]); cnt++; }
    if (mask2[b * SS + s]) { sum += fdecode(colkey[b * SS + s]); cnt++; }
  }
#pragma unroll
  for (int m = 1; m < 64; m <<= 1) {
    sum += __shfl_xor(sum, m);
    cnt += __shfl_xor(cnt, m);
  }
  __shared__ float sS[4];
  __shared__ int sC[4];
  int w = t >> 6, lane = t & 63;
  if (lane == 0) { sS[w] = sum; sC[w] = cnt; }
  __syncthreads();
  if (t == 0) {
    float T = sS[0] + sS[1] + sS[2] + sS[3];
    int C = sC[0] + sC[1] + sC[2] + sC[3];
    out[b] = T / fmaxf((float)C, 1.0f);
  }
}

extern "C" void kernel_launch(void* const* d_in, const int* in_sizes, int n_in,
                              void* d_out, int out_size, void* d_ws, size_t ws_size,
                              hipStream_t stream) {
  const float* emb1 = (const float*)d_in[0];
  const float* emb2 = (const float*)d_in[1];
  const int* mask1 = (const int*)d_in[2];
  const int* mask2 = (const int*)d_in[3];
  float* out = (float*)d_out;

  unsigned short* wsA = (unsigned short*)d_ws;              // 25.2 MB
  unsigned short* wsB = wsA + (size_t)NROW * DD;            // 25.2 MB
  unsigned* rowkey = (unsigned*)(wsB + (size_t)NROW * DD);  // 64 KB
  unsigned* colkey = rowkey + NROW;                         // 64 KB
  int* idx1 = (int*)(colkey + NROW);                        // 64 KB
  int* idx2 = idx1 + NROW;                                  // 64 KB
  int* nt1 = idx2 + NROW;                                   // 128 B
  int* nt2 = nt1 + BB;

  index_kernel<<<64, 64, 0, stream>>>(mask1, mask2, idx1, idx2, nt1, nt2, rowkey, colkey);
  norm_cvt_kernel<<<8192, 256, 0, stream>>>(emb1, emb2, mask1, mask2, wsA, wsB);
  simmax_kernel<<<512, 256, 0, stream>>>(wsA, wsB, idx1, idx2, nt1, nt2, rowkey, colkey);
  finalize_kernel<<<BB, 256, 0, stream>>>(mask1, mask2, rowkey, colkey, out);
}